// Round 1
// baseline (3532.286 us; speedup 1.0000x reference)
//
#include <hip/hip_runtime.h>
#include <cstdint>
#include <cstddef>

// BottomUpNet: N=8192 rows independent; K=16 sequential steps.
// R12: 2-phase double-buffered K-loop (T3 minimum recipe). BK 64->32,
// LDS dbuf (split 48 KB, h 32 KB). STAGE(next) issued BEFORE compute(cur);
// one barrier per tile -> staging latency hides under MFMA instead of a
// full vmcnt(0) drain per tile (R11 was 1-phase: MfmaUtil 32%).
// Accumulation order over k is BIT-IDENTICAL to R11 (tiles walk k in order,
// 2 kh/tile instead of 4): absmax must stay 1.192e-07. Revert if it moves.
// Also: bijective XCD remap (y'=bx&7, x'=bx>>3|by<<3) — each XCD's 64
// blocks share one 128-col B panel (0.55 MB) in its private L2 (T1).
// Swizzle re-derived for BK=32: 4 segs/row, XOR row&3; fragment reads
// verified conflict-free (8 lanes per 4-bank group, 32 banks covered).

typedef _Float16 f16x8 __attribute__((ext_vector_type(8)));
typedef float f32x16 __attribute__((ext_vector_type(16)));

__device__ __forceinline__ void gload16(const void* g, void* l) {
  // async global->LDS, 16B/lane, LDS dest = wave-uniform base + lane*16
  __builtin_amdgcn_global_load_lds(
      (__attribute__((address_space(1))) void*)const_cast<void*>(g),
      (__attribute__((address_space(3))) void*)l,
      16, 0, 0);
}

// ---- m-GEMM: C = relu(A@B^T + bias); A fp16 hi; B hi/lo fp16 (2 MFMAs);
// C stored fp16 hi. Tile 128x128, BK=32 double-buffered, 256 thr (4 waves).
__global__ __launch_bounds__(256, 2)
void gemm_split_kernel(const _Float16* __restrict__ AH0, int ldA0,
                       const _Float16* __restrict__ AH1, int ldA1,
                       int kcut, int Ktot,
                       const _Float16* __restrict__ BH, const _Float16* __restrict__ BL,
                       const float* __restrict__ bias,
                       _Float16* __restrict__ CH, int ldC)
{
  __shared__ _Float16 sAh[2][128 * 32];
  __shared__ _Float16 sBh[2][128 * 32];
  __shared__ _Float16 sBl[2][128 * 32];

  const int lane = threadIdx.x & 63;
  const int wave = threadIdx.x >> 6;
  const int wm = (wave >> 1) * 64, wn = (wave & 1) * 64;

  // XCD remap: physical (bx,by) in (64,8); XCD = bx&7 (round-robin on
  // linear id). Give each XCD one logical column panel -> B L2-resident.
  const int yl = blockIdx.x & 7;
  const int xl = (blockIdx.x >> 3) + (blockIdx.y << 3);
  const int mBase = xl * 128, nBase = yl * 128;

  // staging coords: 16 rows/chunk (64 B rows), 4 lanes/row (16 B each);
  // physical seg in LDS = lane&3, global source seg = (lane&3) ^ (row&3)
  const int lr = lane >> 2;                    // row within chunk (0..15)
  const int lcs = (((lane & 3) ^ (lr & 3)) * 8); // swizzled src offset (halves)
  const int c0 = wave * 2, c1 = wave * 2 + 1;  // two 16-row chunks per wave
  const int r0 = c0 * 16 + lr, r1 = c1 * 16 + lr;

  // fragment coords + read-side swizzle (row&3 == l31&3)
  const int l31 = lane & 31, l5 = lane >> 5;
  const int fswz = l31 & 3;

  // precomputed per-lane source pointers (stage = ptr + kt)
  const _Float16* aP00 = AH0 + (size_t)(mBase + r0) * ldA0 + lcs;
  const _Float16* aP01 = AH0 + (size_t)(mBase + r1) * ldA0 + lcs;
  const _Float16* aP10 = AH1 + (size_t)(mBase + r0) * ldA1 + lcs;
  const _Float16* aP11 = AH1 + (size_t)(mBase + r1) * ldA1 + lcs;
  const _Float16* bHp0 = BH + (size_t)(nBase + r0) * Ktot + lcs;
  const _Float16* bHp1 = BH + (size_t)(nBase + r1) * Ktot + lcs;
  const _Float16* bLp0 = BL + (size_t)(nBase + r0) * Ktot + lcs;
  const _Float16* bLp1 = BL + (size_t)(nBase + r1) * Ktot + lcs;

  f32x16 acc[2][2];
#pragma unroll
  for (int i = 0; i < 2; ++i)
#pragma unroll
    for (int j = 0; j < 2; ++j)
      acc[i][j] = (f32x16)0.0f;

  auto STAGE = [&](int b, int kt) {
    const _Float16 *a0, *a1;
    if (kt < kcut) { a0 = aP00 + kt; a1 = aP01 + kt; }
    else           { a0 = aP10 + (kt - kcut); a1 = aP11 + (kt - kcut); }
    gload16(a0,       &sAh[b][c0 * 512]);
    gload16(a1,       &sAh[b][c1 * 512]);
    gload16(bHp0 + kt, &sBh[b][c0 * 512]);
    gload16(bHp1 + kt, &sBh[b][c1 * 512]);
    gload16(bLp0 + kt, &sBl[b][c0 * 512]);
    gload16(bLp1 + kt, &sBl[b][c1 * 512]);
  };

  auto COMPUTE = [&](int b) {
#pragma unroll
    for (int kh = 0; kh < 2; ++kh) {            // two K=16 MFMAs per BK=32
      const int ko = ((kh * 2 + l5) ^ fswz) * 8; // swizzled seg (0..3)
      f16x8 ah[2], bh[2], bl[2];
#pragma unroll
      for (int i = 0; i < 2; ++i)
        ah[i] = *(const f16x8*)&sAh[b][(wm + i * 32 + l31) * 32 + ko];
#pragma unroll
      for (int j = 0; j < 2; ++j) {
        const int off = (wn + j * 32 + l31) * 32 + ko;
        bh[j] = *(const f16x8*)&sBh[b][off];
        bl[j] = *(const f16x8*)&sBl[b][off];
      }
#pragma unroll
      for (int i = 0; i < 2; ++i)
#pragma unroll
        for (int j = 0; j < 2; ++j) {
          acc[i][j] = __builtin_amdgcn_mfma_f32_32x32x16_f16(ah[i], bl[j], acc[i][j], 0, 0, 0);
          acc[i][j] = __builtin_amdgcn_mfma_f32_32x32x16_f16(ah[i], bh[j], acc[i][j], 0, 0, 0);
        }
    }
  };

  const int NT = Ktot >> 5;
  STAGE(0, 0);
  __syncthreads();                 // vmcnt(0) drain: buf0 ready
  int cur = 0;
  for (int t = 1; t < NT; ++t) {
    STAGE(cur ^ 1, t * 32);        // prefetch flies under compute
    COMPUTE(cur);
    __syncthreads();               // drains prefetch + all reads of cur
    cur ^= 1;
  }
  COMPUTE(cur);

  float bv[2];
#pragma unroll
  for (int j = 0; j < 2; ++j) bv[j] = bias[nBase + wn + j * 32 + l31];
#pragma unroll
  for (int i = 0; i < 2; ++i)
#pragma unroll
    for (int j = 0; j < 2; ++j)
#pragma unroll
      for (int r = 0; r < 16; ++r) {
        const int row = mBase + wm + i * 32 + (r & 3) + 8 * (r >> 2) + 4 * l5;
        const int col = nBase + wn + j * 32 + l31;
        float v = fmaxf(acc[i][j][r] + bv[j], 0.0f);
        CH[(size_t)row * ldC + col] = (_Float16)v;
      }
}

// ---- fp16 GEMM (hi-only, 1 MFMA): C = relu(A@B^T + bias) fp16 out,
// or fused-pred mode (sacc != null): sacc[row] += sum_col relu(.)*w3[col]
__global__ __launch_bounds__(256, 2)
void gemm_h_kernel(const _Float16* __restrict__ A0, int ldA0,
                   const _Float16* __restrict__ A1, int ldA1,
                   int kcut, int Ktot,
                   const _Float16* __restrict__ B,
                   const float* __restrict__ bias,
                   _Float16* __restrict__ C, int ldC,
                   const float* __restrict__ w3, float* __restrict__ sacc)
{
  __shared__ _Float16 sAh[2][128 * 32];
  __shared__ _Float16 sBh[2][128 * 32];

  const int lane = threadIdx.x & 63;
  const int wave = threadIdx.x >> 6;
  const int wm = (wave >> 1) * 64, wn = (wave & 1) * 64;

  const int yl = blockIdx.x & 7;
  const int xl = (blockIdx.x >> 3) + (blockIdx.y << 3);
  const int mBase = xl * 128, nBase = yl * 128;

  const int lr = lane >> 2;
  const int lcs = (((lane & 3) ^ (lr & 3)) * 8);
  const int c0 = wave * 2, c1 = wave * 2 + 1;
  const int r0 = c0 * 16 + lr, r1 = c1 * 16 + lr;

  const int l31 = lane & 31, l5 = lane >> 5;
  const int fswz = l31 & 3;

  const _Float16* aP00 = A0 + (size_t)(mBase + r0) * ldA0 + lcs;
  const _Float16* aP01 = A0 + (size_t)(mBase + r1) * ldA0 + lcs;
  const _Float16* aP10 = A1 + (size_t)(mBase + r0) * ldA1 + lcs;
  const _Float16* aP11 = A1 + (size_t)(mBase + r1) * ldA1 + lcs;
  const _Float16* bHp0 = B + (size_t)(nBase + r0) * Ktot + lcs;
  const _Float16* bHp1 = B + (size_t)(nBase + r1) * Ktot + lcs;

  f32x16 acc[2][2];
#pragma unroll
  for (int i = 0; i < 2; ++i)
#pragma unroll
    for (int j = 0; j < 2; ++j)
      acc[i][j] = (f32x16)0.0f;

  auto STAGE = [&](int b, int kt) {
    const _Float16 *a0, *a1;
    if (kt < kcut) { a0 = aP00 + kt; a1 = aP01 + kt; }
    else           { a0 = aP10 + (kt - kcut); a1 = aP11 + (kt - kcut); }
    gload16(a0,       &sAh[b][c0 * 512]);
    gload16(a1,       &sAh[b][c1 * 512]);
    gload16(bHp0 + kt, &sBh[b][c0 * 512]);
    gload16(bHp1 + kt, &sBh[b][c1 * 512]);
  };

  auto COMPUTE = [&](int b) {
#pragma unroll
    for (int kh = 0; kh < 2; ++kh) {
      const int ko = ((kh * 2 + l5) ^ fswz) * 8;
      f16x8 ah[2], bh[2];
#pragma unroll
      for (int i = 0; i < 2; ++i)
        ah[i] = *(const f16x8*)&sAh[b][(wm + i * 32 + l31) * 32 + ko];
#pragma unroll
      for (int j = 0; j < 2; ++j)
        bh[j] = *(const f16x8*)&sBh[b][(wn + j * 32 + l31) * 32 + ko];
#pragma unroll
      for (int i = 0; i < 2; ++i)
#pragma unroll
        for (int j = 0; j < 2; ++j)
          acc[i][j] = __builtin_amdgcn_mfma_f32_32x32x16_f16(ah[i], bh[j], acc[i][j], 0, 0, 0);
    }
  };

  const int NT = Ktot >> 5;
  STAGE(0, 0);
  __syncthreads();
  int cur = 0;
  for (int t = 1; t < NT; ++t) {
    STAGE(cur ^ 1, t * 32);
    COMPUTE(cur);
    __syncthreads();
    cur ^= 1;
  }
  COMPUTE(cur);

  float bv[2], w3v[2];
#pragma unroll
  for (int j = 0; j < 2; ++j) {
    const int col = nBase + wn + j * 32 + l31;
    bv[j] = bias[col];
    w3v[j] = sacc ? w3[col] : 0.0f;
  }

  if (sacc) {
    // fused pred partial: one value per C/D row, reduced over the 32 col-lanes
#pragma unroll
    for (int i = 0; i < 2; ++i)
#pragma unroll
      for (int r = 0; r < 16; ++r) {
        float pr = 0.0f;
#pragma unroll
        for (int j = 0; j < 2; ++j)
          pr += fmaxf(acc[i][j][r] + bv[j], 0.0f) * w3v[j];
        pr += __shfl_xor(pr, 1);
        pr += __shfl_xor(pr, 2);
        pr += __shfl_xor(pr, 4);
        pr += __shfl_xor(pr, 8);
        pr += __shfl_xor(pr, 16);
        if (l31 == 0)
          atomicAdd(&sacc[mBase + wm + i * 32 + (r & 3) + 8 * (r >> 2) + 4 * l5], pr);
      }
  } else {
#pragma unroll
    for (int i = 0; i < 2; ++i)
#pragma unroll
      for (int j = 0; j < 2; ++j)
#pragma unroll
        for (int r = 0; r < 16; ++r) {
          const int row = mBase + wm + i * 32 + (r & 3) + 8 * (r >> 2) + 4 * l5;
          const int col = nBase + wn + j * 32 + l31;
          float v = fmaxf(acc[i][j][r] + bv[j], 0.0f);
          C[(size_t)row * ldC + col] = (_Float16)v;
        }
  }
}

// W (K x N fp32, row-major) -> out (N x K fp16 hi[/lo]), i.e. transposed
__global__ void wconv_kernel(const float* __restrict__ W, int K, int N,
                             _Float16* __restrict__ oH, _Float16* __restrict__ oL) {
  int idx = blockIdx.x * 256 + threadIdx.x;   // idx = n*K + k (output-coalesced)
  if (idx >= K * N) return;
  int n = idx / K, k = idx - n * K;
  float v = W[(size_t)k * N + n];
  _Float16 h = (_Float16)v;
  oH[idx] = h;
  if (oL) oL[idx] = (_Float16)(v - (float)h);
}

__global__ void init_summary_kernel(const float* __restrict__ agg,
                                    _Float16* __restrict__ sH,
                                    float* __restrict__ sacc) {
  int idx = blockIdx.x * 256 + threadIdx.x;   // 8192*1024
  sH[idx] = (_Float16)agg[idx & 1023];
  if (idx < 8192) sacc[idx] = 0.0f;
}

// towers [n][k][f] fp32 -> towAll [k][n][f] fp16 hi (all 16 slices)
__global__ void tow_conv_all_kernel(const float* __restrict__ towers,
                                    _Float16* __restrict__ oH) {
  size_t idx = (size_t)blockIdx.x * 256 + threadIdx.x;  // (k*8192+n)*64+f
  int f = idx & 63;
  int n = (int)((idx >> 6) & 8191);
  int k = (int)(idx >> 19);
  oH[idx] = (_Float16)towers[((size_t)n * 16 + k) * 64 + f];
}

// pred = sigmoid(sacc + Ob3); out *= pred; re-zero sacc for next step
__global__ void pred_final_kernel(float* __restrict__ sacc, const float* __restrict__ b3,
                                  float* __restrict__ out, int step) {
  int row = blockIdx.x * 256 + threadIdx.x;   // 8192
  float p = 1.0f / (1.0f + expf(-(sacc[row] + b3[0])));
  out[row] = (step == 0) ? p : out[row] * p;
  sacc[row] = 0.0f;
}

extern "C" void kernel_launch(void* const* d_in, const int* in_sizes, int n_in,
                              void* d_out, int out_size, void* d_ws, size_t ws_size,
                              hipStream_t stream) {
  const float* towers = (const float*)d_in[0];
  const float* agg    = (const float*)d_in[1];
  const float* MW1 = (const float*)d_in[2];
  const float* Mb1 = (const float*)d_in[3];
  const float* MW2 = (const float*)d_in[4];
  const float* Mb2 = (const float*)d_in[5];
  const float* MW3 = (const float*)d_in[6];
  const float* Mb3 = (const float*)d_in[7];
  const float* OW1 = (const float*)d_in[8];
  const float* Ob1 = (const float*)d_in[9];
  const float* OW2 = (const float*)d_in[10];
  const float* Ob2 = (const float*)d_in[11];
  const float* OW3 = (const float*)d_in[12];
  const float* Ob3 = (const float*)d_in[13];
  float* out = (float*)d_out;

  // ws layout (~110 MiB)
  _Float16* p = (_Float16*)d_ws;
  _Float16* MW1tH = p; p += (size_t)1024 * 1088;
  _Float16* MW1tL = p; p += (size_t)1024 * 1088;
  _Float16* OW1tH = p; p += (size_t)1024 * 1088;
  _Float16* MW2tH = p; p += (size_t)1024 * 1024;
  _Float16* MW2tL = p; p += (size_t)1024 * 1024;
  _Float16* OW2tH = p; p += (size_t)1024 * 1024;
  _Float16* MW3tH = p; p += (size_t)1024 * 1024;
  _Float16* MW3tL = p; p += (size_t)1024 * 1024;
  _Float16* sumH  = p; p += (size_t)8192 * 1024;
  _Float16* m1H   = p; p += (size_t)8192 * 1024;
  _Float16* h1    = p; p += (size_t)8192 * 1024;
  _Float16* m2H   = p; p += (size_t)8192 * 1024;
  _Float16* towAllH = p; p += (size_t)16 * 8192 * 64;
  float* sacc = (float*)p;

  // per-call setup: transpose+split weights, convert towers, init summary
  {
    int tot = 1088 * 1024;
    wconv_kernel<<<dim3((tot + 255) / 256), dim3(256), 0, stream>>>(MW1, 1088, 1024, MW1tH, MW1tL);
    wconv_kernel<<<dim3((tot + 255) / 256), dim3(256), 0, stream>>>(OW1, 1088, 1024, OW1tH, nullptr);
    tot = 1024 * 1024;
    wconv_kernel<<<dim3((tot + 255) / 256), dim3(256), 0, stream>>>(MW2, 1024, 1024, MW2tH, MW2tL);
    wconv_kernel<<<dim3((tot + 255) / 256), dim3(256), 0, stream>>>(OW2, 1024, 1024, OW2tH, nullptr);
    wconv_kernel<<<dim3((tot + 255) / 256), dim3(256), 0, stream>>>(MW3, 1024, 1024, MW3tH, MW3tL);
    init_summary_kernel<<<dim3(32768), dim3(256), 0, stream>>>(agg, sumH, sacc);
    tow_conv_all_kernel<<<dim3(32768), dim3(256), 0, stream>>>(towers, towAllH);
  }

  const dim3 G(64, 8), B256(256);   // 128x128 tiles over 8192x1024 -> 512 blocks
  for (int k = 0; k < 16; ++k) {
    const _Float16* towH = towAllH + (size_t)k * 8192 * 64;

    // K1m: x=[sum|tow] @ MW1^T -> m1 (2-MFMA: weight-lo kept)
    gemm_split_kernel<<<G, B256, 0, stream>>>(sumH, 1024, towH, 64,
                                              1024, 1088, MW1tH, MW1tL, Mb1, m1H, 1024);
    // K1h: x=[sum|tow] @ OW1^T -> h1 (fp16)
    gemm_h_kernel<<<G, B256, 0, stream>>>(sumH, 1024, towH, 64, 1024, 1088,
                                          OW1tH, Ob1, h1, 1024, nullptr, nullptr);
    // K2m: m1 @ MW2^T -> m2 (2-MFMA)
    gemm_split_kernel<<<G, B256, 0, stream>>>(m1H, 1024, m1H, 1024,
                                              1024, 1024, MW2tH, MW2tL, Mb2, m2H, 1024);
    // K2h: h1 @ OW2^T -> fused relu+dot(OW3) into sacc (fp16)
    gemm_h_kernel<<<G, B256, 0, stream>>>(h1, 1024, h1, 1024, 1024, 1024,
                                          OW2tH, Ob2, nullptr, 1024, OW3, sacc);
    // K3: m2 @ MW3^T -> summary (2-MFMA; in-place: K1m/K1h already consumed it)
    gemm_split_kernel<<<G, B256, 0, stream>>>(m2H, 1024, m2H, 1024,
                                              1024, 1024, MW3tH, MW3tL, Mb3, sumH, 1024);
    // pred + product accumulate + re-zero sacc
    pred_final_kernel<<<dim3(32), B256, 0, stream>>>(sacc, Ob3, out, k);
  }
}

// Round 2
// 2915.953 us; speedup vs baseline: 1.2114x; 1.2114x over previous
//
#include <hip/hip_runtime.h>
#include <cstdint>
#include <cstddef>

// BottomUpNet: N=8192 rows independent; K=16 sequential steps.
// R13: keep R12's 2-phase double-buffered K-loop (BK=32), FIX both R12
// regressions found by rocprof post-mortem:
//  (a) XCD remap REVERTED. R11's natural G(64,8) order already pins an
//      A-slice per XCD (block bx of every N-panel -> XCD bx%8, same
//      2.2 MB A rows re-read from its own L2). R12's remap made every
//      XCD stream all 17.8 MB of A -> FETCH_SIZE 26->72 MB. Reverted.
//  (b) BK=32 swizzle was 8-way bank-conflicted (rows r, r+4 collided:
//      SQ_LDS_BANK_CONFLICT 3.3M->10M). New paired-row layout: logical
//      rows 2r,2r+1 packed into one 128-B physical row; k-seg stored at
//      p = g ^ (phys_row&3). Verified: each wave64 ds_read_b128 puts
//      8 lanes on each 4-bank group = 32 B/bank = 8-cyc minimum.
//      global_load_lds dest stays linear; source carries inverse swizzle.
// Accumulation order over k is BIT-IDENTICAL to R11/R12: absmax must
// stay 1.192093e-07 — revert if it moves.

typedef _Float16 f16x8 __attribute__((ext_vector_type(8)));
typedef float f32x16 __attribute__((ext_vector_type(16)));

__device__ __forceinline__ void gload16(const void* g, void* l) {
  // async global->LDS, 16B/lane, LDS dest = wave-uniform base + lane*16
  __builtin_amdgcn_global_load_lds(
      (__attribute__((address_space(1))) void*)const_cast<void*>(g),
      (__attribute__((address_space(3))) void*)l,
      16, 0, 0);
}

// ---- m-GEMM: C = relu(A@B^T + bias); A fp16 hi; B hi/lo fp16 (2 MFMAs);
// C stored fp16 hi. Tile 128x128, BK=32 double-buffered, 256 thr (4 waves).
__global__ __launch_bounds__(256, 3)
void gemm_split_kernel(const _Float16* __restrict__ AH0, int ldA0,
                       const _Float16* __restrict__ AH1, int ldA1,
                       int kcut, int Ktot,
                       const _Float16* __restrict__ BH, const _Float16* __restrict__ BL,
                       const float* __restrict__ bias,
                       _Float16* __restrict__ CH, int ldC)
{
  __shared__ _Float16 sAh[2][128 * 32];
  __shared__ _Float16 sBh[2][128 * 32];
  __shared__ _Float16 sBl[2][128 * 32];

  const int lane = threadIdx.x & 63;
  const int wave = threadIdx.x >> 6;
  const int wm = (wave >> 1) * 64, wn = (wave & 1) * 64;
  const int mBase = blockIdx.x * 128, nBase = blockIdx.y * 128;

  // staging (paired-row layout): chunk = 16 logical rows = 8 phys 128-B rows.
  // lane l -> phys byte l*16: phys row l>>3, seg8 l&7.
  //   logical row in chunk = 2*(l>>3) + ((l>>2)&1)
  //   stored seg p = l&3 holds global seg g = p ^ ((l>>3)&3)
  const int lr  = 2 * (lane >> 3) + ((lane >> 2) & 1);     // logical row 0..15
  const int lcs = (((lane & 3) ^ ((lane >> 3) & 3)) * 8);  // src k-seg (halves)
  const int c0 = wave * 2, c1 = wave * 2 + 1;              // chunks per wave
  const int r0 = c0 * 16 + lr, r1 = c1 * 16 + lr;

  // fragment read coords: logical row r = base + l31 (base mult of 32)
  //   off_halves = (r>>1)*64 + (r&1)*32 + (g ^ ((r>>1)&3))*8
  const int l31 = lane & 31, l5 = lane >> 5;
  const int rowoff = (l31 >> 1) * 64 + (l31 & 1) * 32;     // lane-const part
  const int fswz = (l31 >> 1) & 3;

  const _Float16* aP00 = AH0 + (size_t)(mBase + r0) * ldA0 + lcs;
  const _Float16* aP01 = AH0 + (size_t)(mBase + r1) * ldA0 + lcs;
  const _Float16* aP10 = AH1 + (size_t)(mBase + r0) * ldA1 + lcs;
  const _Float16* aP11 = AH1 + (size_t)(mBase + r1) * ldA1 + lcs;
  const _Float16* bHp0 = BH + (size_t)(nBase + r0) * Ktot + lcs;
  const _Float16* bHp1 = BH + (size_t)(nBase + r1) * Ktot + lcs;
  const _Float16* bLp0 = BL + (size_t)(nBase + r0) * Ktot + lcs;
  const _Float16* bLp1 = BL + (size_t)(nBase + r1) * Ktot + lcs;

  f32x16 acc[2][2];
#pragma unroll
  for (int i = 0; i < 2; ++i)
#pragma unroll
    for (int j = 0; j < 2; ++j)
      acc[i][j] = (f32x16)0.0f;

  auto STAGE = [&](int b, int kt) {
    const _Float16 *a0, *a1;
    if (kt < kcut) { a0 = aP00 + kt; a1 = aP01 + kt; }
    else           { a0 = aP10 + (kt - kcut); a1 = aP11 + (kt - kcut); }
    gload16(a0,        &sAh[b][c0 * 512]);
    gload16(a1,        &sAh[b][c1 * 512]);
    gload16(bHp0 + kt, &sBh[b][c0 * 512]);
    gload16(bHp1 + kt, &sBh[b][c1 * 512]);
    gload16(bLp0 + kt, &sBl[b][c0 * 512]);
    gload16(bLp1 + kt, &sBl[b][c1 * 512]);
  };

  auto COMPUTE = [&](int b) {
#pragma unroll
    for (int kh = 0; kh < 2; ++kh) {            // two K=16 MFMAs per BK=32
      const int g = kh * 2 + l5;
      const int ko = ((g ^ fswz) * 8);
      f16x8 ah[2], bh[2], bl[2];
#pragma unroll
      for (int i = 0; i < 2; ++i)
        ah[i] = *(const f16x8*)&sAh[b][(wm + i * 32) * 32 + rowoff + ko];
#pragma unroll
      for (int j = 0; j < 2; ++j) {
        const int off = (wn + j * 32) * 32 + rowoff + ko;
        bh[j] = *(const f16x8*)&sBh[b][off];
        bl[j] = *(const f16x8*)&sBl[b][off];
      }
#pragma unroll
      for (int i = 0; i < 2; ++i)
#pragma unroll
        for (int j = 0; j < 2; ++j) {
          acc[i][j] = __builtin_amdgcn_mfma_f32_32x32x16_f16(ah[i], bl[j], acc[i][j], 0, 0, 0);
          acc[i][j] = __builtin_amdgcn_mfma_f32_32x32x16_f16(ah[i], bh[j], acc[i][j], 0, 0, 0);
        }
    }
  };

  const int NT = Ktot >> 5;
  STAGE(0, 0);
  __syncthreads();                 // buf0 ready
  int cur = 0;
  for (int t = 1; t < NT; ++t) {
    STAGE(cur ^ 1, t * 32);        // prefetch flies under compute
    COMPUTE(cur);
    __syncthreads();               // drains prefetch + all reads of cur
    cur ^= 1;
  }
  COMPUTE(cur);

  float bv[2];
#pragma unroll
  for (int j = 0; j < 2; ++j) bv[j] = bias[nBase + wn + j * 32 + l31];
#pragma unroll
  for (int i = 0; i < 2; ++i)
#pragma unroll
    for (int j = 0; j < 2; ++j)
#pragma unroll
      for (int r = 0; r < 16; ++r) {
        const int row = mBase + wm + i * 32 + (r & 3) + 8 * (r >> 2) + 4 * l5;
        const int col = nBase + wn + j * 32 + l31;
        float v = fmaxf(acc[i][j][r] + bv[j], 0.0f);
        CH[(size_t)row * ldC + col] = (_Float16)v;
      }
}

// ---- fp16 GEMM (hi-only, 1 MFMA): C = relu(A@B^T + bias) fp16 out,
// or fused-pred mode (sacc != null): sacc[row] += sum_col relu(.)*w3[col]
__global__ __launch_bounds__(256, 3)
void gemm_h_kernel(const _Float16* __restrict__ A0, int ldA0,
                   const _Float16* __restrict__ A1, int ldA1,
                   int kcut, int Ktot,
                   const _Float16* __restrict__ B,
                   const float* __restrict__ bias,
                   _Float16* __restrict__ C, int ldC,
                   const float* __restrict__ w3, float* __restrict__ sacc)
{
  __shared__ _Float16 sAh[2][128 * 32];
  __shared__ _Float16 sBh[2][128 * 32];

  const int lane = threadIdx.x & 63;
  const int wave = threadIdx.x >> 6;
  const int wm = (wave >> 1) * 64, wn = (wave & 1) * 64;
  const int mBase = blockIdx.x * 128, nBase = blockIdx.y * 128;

  const int lr  = 2 * (lane >> 3) + ((lane >> 2) & 1);
  const int lcs = (((lane & 3) ^ ((lane >> 3) & 3)) * 8);
  const int c0 = wave * 2, c1 = wave * 2 + 1;
  const int r0 = c0 * 16 + lr, r1 = c1 * 16 + lr;

  const int l31 = lane & 31, l5 = lane >> 5;
  const int rowoff = (l31 >> 1) * 64 + (l31 & 1) * 32;
  const int fswz = (l31 >> 1) & 3;

  const _Float16* aP00 = A0 + (size_t)(mBase + r0) * ldA0 + lcs;
  const _Float16* aP01 = A0 + (size_t)(mBase + r1) * ldA0 + lcs;
  const _Float16* aP10 = A1 + (size_t)(mBase + r0) * ldA1 + lcs;
  const _Float16* aP11 = A1 + (size_t)(mBase + r1) * ldA1 + lcs;
  const _Float16* bHp0 = B + (size_t)(nBase + r0) * Ktot + lcs;
  const _Float16* bHp1 = B + (size_t)(nBase + r1) * Ktot + lcs;

  f32x16 acc[2][2];
#pragma unroll
  for (int i = 0; i < 2; ++i)
#pragma unroll
    for (int j = 0; j < 2; ++j)
      acc[i][j] = (f32x16)0.0f;

  auto STAGE = [&](int b, int kt) {
    const _Float16 *a0, *a1;
    if (kt < kcut) { a0 = aP00 + kt; a1 = aP01 + kt; }
    else           { a0 = aP10 + (kt - kcut); a1 = aP11 + (kt - kcut); }
    gload16(a0,        &sAh[b][c0 * 512]);
    gload16(a1,        &sAh[b][c1 * 512]);
    gload16(bHp0 + kt, &sBh[b][c0 * 512]);
    gload16(bHp1 + kt, &sBh[b][c1 * 512]);
  };

  auto COMPUTE = [&](int b) {
#pragma unroll
    for (int kh = 0; kh < 2; ++kh) {
      const int g = kh * 2 + l5;
      const int ko = ((g ^ fswz) * 8);
      f16x8 ah[2], bh[2];
#pragma unroll
      for (int i = 0; i < 2; ++i)
        ah[i] = *(const f16x8*)&sAh[b][(wm + i * 32) * 32 + rowoff + ko];
#pragma unroll
      for (int j = 0; j < 2; ++j)
        bh[j] = *(const f16x8*)&sBh[b][(wn + j * 32) * 32 + rowoff + ko];
#pragma unroll
      for (int i = 0; i < 2; ++i)
#pragma unroll
        for (int j = 0; j < 2; ++j)
          acc[i][j] = __builtin_amdgcn_mfma_f32_32x32x16_f16(ah[i], bh[j], acc[i][j], 0, 0, 0);
    }
  };

  const int NT = Ktot >> 5;
  STAGE(0, 0);
  __syncthreads();
  int cur = 0;
  for (int t = 1; t < NT; ++t) {
    STAGE(cur ^ 1, t * 32);
    COMPUTE(cur);
    __syncthreads();
    cur ^= 1;
  }
  COMPUTE(cur);

  float bv[2], w3v[2];
#pragma unroll
  for (int j = 0; j < 2; ++j) {
    const int col = nBase + wn + j * 32 + l31;
    bv[j] = bias[col];
    w3v[j] = sacc ? w3[col] : 0.0f;
  }

  if (sacc) {
    // fused pred partial: one value per C/D row, reduced over the 32 col-lanes
#pragma unroll
    for (int i = 0; i < 2; ++i)
#pragma unroll
      for (int r = 0; r < 16; ++r) {
        float pr = 0.0f;
#pragma unroll
        for (int j = 0; j < 2; ++j)
          pr += fmaxf(acc[i][j][r] + bv[j], 0.0f) * w3v[j];
        pr += __shfl_xor(pr, 1);
        pr += __shfl_xor(pr, 2);
        pr += __shfl_xor(pr, 4);
        pr += __shfl_xor(pr, 8);
        pr += __shfl_xor(pr, 16);
        if (l31 == 0)
          atomicAdd(&sacc[mBase + wm + i * 32 + (r & 3) + 8 * (r >> 2) + 4 * l5], pr);
      }
  } else {
#pragma unroll
    for (int i = 0; i < 2; ++i)
#pragma unroll
      for (int j = 0; j < 2; ++j)
#pragma unroll
        for (int r = 0; r < 16; ++r) {
          const int row = mBase + wm + i * 32 + (r & 3) + 8 * (r >> 2) + 4 * l5;
          const int col = nBase + wn + j * 32 + l31;
          float v = fmaxf(acc[i][j][r] + bv[j], 0.0f);
          C[(size_t)row * ldC + col] = (_Float16)v;
        }
  }
}

// W (K x N fp32, row-major) -> out (N x K fp16 hi[/lo]), i.e. transposed
__global__ void wconv_kernel(const float* __restrict__ W, int K, int N,
                             _Float16* __restrict__ oH, _Float16* __restrict__ oL) {
  int idx = blockIdx.x * 256 + threadIdx.x;   // idx = n*K + k (output-coalesced)
  if (idx >= K * N) return;
  int n = idx / K, k = idx - n * K;
  float v = W[(size_t)k * N + n];
  _Float16 h = (_Float16)v;
  oH[idx] = h;
  if (oL) oL[idx] = (_Float16)(v - (float)h);
}

__global__ void init_summary_kernel(const float* __restrict__ agg,
                                    _Float16* __restrict__ sH,
                                    float* __restrict__ sacc) {
  int idx = blockIdx.x * 256 + threadIdx.x;   // 8192*1024
  sH[idx] = (_Float16)agg[idx & 1023];
  if (idx < 8192) sacc[idx] = 0.0f;
}

// towers [n][k][f] fp32 -> towAll [k][n][f] fp16 hi (all 16 slices)
__global__ void tow_conv_all_kernel(const float* __restrict__ towers,
                                    _Float16* __restrict__ oH) {
  size_t idx = (size_t)blockIdx.x * 256 + threadIdx.x;  // (k*8192+n)*64+f
  int f = idx & 63;
  int n = (int)((idx >> 6) & 8191);
  int k = (int)(idx >> 19);
  oH[idx] = (_Float16)towers[((size_t)n * 16 + k) * 64 + f];
}

// pred = sigmoid(sacc + Ob3); out *= pred; re-zero sacc for next step
__global__ void pred_final_kernel(float* __restrict__ sacc, const float* __restrict__ b3,
                                  float* __restrict__ out, int step) {
  int row = blockIdx.x * 256 + threadIdx.x;   // 8192
  float p = 1.0f / (1.0f + expf(-(sacc[row] + b3[0])));
  out[row] = (step == 0) ? p : out[row] * p;
  sacc[row] = 0.0f;
}

extern "C" void kernel_launch(void* const* d_in, const int* in_sizes, int n_in,
                              void* d_out, int out_size, void* d_ws, size_t ws_size,
                              hipStream_t stream) {
  const float* towers = (const float*)d_in[0];
  const float* agg    = (const float*)d_in[1];
  const float* MW1 = (const float*)d_in[2];
  const float* Mb1 = (const float*)d_in[3];
  const float* MW2 = (const float*)d_in[4];
  const float* Mb2 = (const float*)d_in[5];
  const float* MW3 = (const float*)d_in[6];
  const float* Mb3 = (const float*)d_in[7];
  const float* OW1 = (const float*)d_in[8];
  const float* Ob1 = (const float*)d_in[9];
  const float* OW2 = (const float*)d_in[10];
  const float* Ob2 = (const float*)d_in[11];
  const float* OW3 = (const float*)d_in[12];
  const float* Ob3 = (const float*)d_in[13];
  float* out = (float*)d_out;

  // ws layout (~110 MiB)
  _Float16* p = (_Float16*)d_ws;
  _Float16* MW1tH = p; p += (size_t)1024 * 1088;
  _Float16* MW1tL = p; p += (size_t)1024 * 1088;
  _Float16* OW1tH = p; p += (size_t)1024 * 1088;
  _Float16* MW2tH = p; p += (size_t)1024 * 1024;
  _Float16* MW2tL = p; p += (size_t)1024 * 1024;
  _Float16* OW2tH = p; p += (size_t)1024 * 1024;
  _Float16* MW3tH = p; p += (size_t)1024 * 1024;
  _Float16* MW3tL = p; p += (size_t)1024 * 1024;
  _Float16* sumH  = p; p += (size_t)8192 * 1024;
  _Float16* m1H   = p; p += (size_t)8192 * 1024;
  _Float16* h1    = p; p += (size_t)8192 * 1024;
  _Float16* m2H   = p; p += (size_t)8192 * 1024;
  _Float16* towAllH = p; p += (size_t)16 * 8192 * 64;
  float* sacc = (float*)p;

  // per-call setup: transpose+split weights, convert towers, init summary
  {
    int tot = 1088 * 1024;
    wconv_kernel<<<dim3((tot + 255) / 256), dim3(256), 0, stream>>>(MW1, 1088, 1024, MW1tH, MW1tL);
    wconv_kernel<<<dim3((tot + 255) / 256), dim3(256), 0, stream>>>(OW1, 1088, 1024, OW1tH, nullptr);
    tot = 1024 * 1024;
    wconv_kernel<<<dim3((tot + 255) / 256), dim3(256), 0, stream>>>(MW2, 1024, 1024, MW2tH, MW2tL);
    wconv_kernel<<<dim3((tot + 255) / 256), dim3(256), 0, stream>>>(OW2, 1024, 1024, OW2tH, nullptr);
    wconv_kernel<<<dim3((tot + 255) / 256), dim3(256), 0, stream>>>(MW3, 1024, 1024, MW3tH, MW3tL);
    init_summary_kernel<<<dim3(32768), dim3(256), 0, stream>>>(agg, sumH, sacc);
    tow_conv_all_kernel<<<dim3(32768), dim3(256), 0, stream>>>(towers, towAllH);
  }

  const dim3 G(64, 8), B256(256);   // 128x128 tiles over 8192x1024 -> 512 blocks
  for (int k = 0; k < 16; ++k) {
    const _Float16* towH = towAllH + (size_t)k * 8192 * 64;

    // K1m: x=[sum|tow] @ MW1^T -> m1 (2-MFMA: weight-lo kept)
    gemm_split_kernel<<<G, B256, 0, stream>>>(sumH, 1024, towH, 64,
                                              1024, 1088, MW1tH, MW1tL, Mb1, m1H, 1024);
    // K1h: x=[sum|tow] @ OW1^T -> h1 (fp16)
    gemm_h_kernel<<<G, B256, 0, stream>>>(sumH, 1024, towH, 64, 1024, 1088,
                                          OW1tH, Ob1, h1, 1024, nullptr, nullptr);
    // K2m: m1 @ MW2^T -> m2 (2-MFMA)
    gemm_split_kernel<<<G, B256, 0, stream>>>(m1H, 1024, m1H, 1024,
                                              1024, 1024, MW2tH, MW2tL, Mb2, m2H, 1024);
    // K2h: h1 @ OW2^T -> fused relu+dot(OW3) into sacc (fp16)
    gemm_h_kernel<<<G, B256, 0, stream>>>(h1, 1024, h1, 1024, 1024, 1024,
                                          OW2tH, Ob2, nullptr, 1024, OW3, sacc);
    // K3: m2 @ MW3^T -> summary (2-MFMA; in-place: K1m/K1h already consumed it)
    gemm_split_kernel<<<G, B256, 0, stream>>>(m2H, 1024, m2H, 1024,
                                              1024, 1024, MW3tH, MW3tL, Mb3, sumH, 1024);
    // pred + product accumulate + re-zero sacc
    pred_final_kernel<<<dim3(32), B256, 0, stream>>>(sacc, Ob3, out, k);
  }
}